// Round 15
// baseline (263.237 us; speedup 1.0000x reference)
//
#include <hip/hip_runtime.h>
#include <math.h>

#define NN   65536
#define BB   128
#define GGR  512
#define EE   65536
#define INF_ 512
#define HIDD 64

typedef __attribute__((ext_vector_type(8))) short bf16x8;
typedef __attribute__((ext_vector_type(4))) float f32x4;
typedef unsigned short ushort_t;
typedef unsigned int uint_t;

static __device__ __forceinline__ float sigmoidf_(float x){ return 1.0f/(1.0f+__expf(-x)); }
static __device__ __forceinline__ float lrelu_(float x){ return x>=0.0f ? x : 0.2f*x; }
static __device__ __forceinline__ float tanhf_(float x){
  float e = __expf(2.f*x);
  return 1.f - 2.f/(e + 1.f);
}

// f32 -> bf16 bits, round-to-nearest-even
static __device__ __forceinline__ ushort_t f2b(float f){
  union { float f; uint_t u; } v; v.f = f;
  uint_t u = v.u;
  uint_t r = (u + 0x7fffu + ((u >> 16) & 1u)) >> 16;
  return (ushort_t)r;
}
// bf16 bits -> f32 (exact)
static __device__ __forceinline__ float b2f(uint_t u16){
  union { uint_t u; float f; } v; v.u = u16 << 16; return v.f;
}

// ---- fused prep: weight transpose+casts, plus hc1/hc2 (blocks >= 832) ----
__global__ void k_prep(const float* __restrict__ W1, const float* __restrict__ W2,
                       const float* __restrict__ Wp1, const float* __restrict__ Wp2,
                       const float* __restrict__ Wfc,
                       ushort_t* __restrict__ W1t, ushort_t* __restrict__ W2t,
                       ushort_t* __restrict__ Wp1t, ushort_t* __restrict__ Wp2t,
                       ushort_t* __restrict__ Wfct,
                       const float* __restrict__ root, const float* __restrict__ Wc1,
                       const float* __restrict__ Wc2, float* __restrict__ hc1,
                       float* __restrict__ hc2){
  if (blockIdx.x >= 832){
    int b = blockIdx.x - 832;
    int f = threadIdx.x;
    if (f < 64){
      const float* r = root + (size_t)b*INF_;
      float a1 = 0.f, a2 = 0.f;
      for (int k = 0; k < INF_; ++k){
        float rv = r[k];
        a1 = fmaf(rv, Wc1[k*HIDD+f], a1);
        a2 = fmaf(rv, Wc2[k*HIDD+f], a2);
      }
      hc1[b*HIDD+f] = a1; hc2[b*HIDD+f] = a2;
    }
    return;
  }
  int idx = blockIdx.x*256 + threadIdx.x;
  if (idx < 32768){                     // W1 [128,256]
    int k = idx >> 8, c = idx & 255;
    W1t[(size_t)c*128 + k] = f2b(W1[idx]);
  } else if (idx < 163840){             // W2 [512,256]
    int j = idx - 32768; int k = j >> 8, c = j & 255;
    W2t[(size_t)c*512 + k] = f2b(W2[j]);
  } else if (idx < 196608){             // W_post1 [512,64]
    int j = idx - 163840; int k = j >> 6, c = j & 63;
    Wp1t[(size_t)c*512 + k] = f2b(Wp1[j]);
  } else if (idx < 200704){             // W_post2 [64,64]
    int j = idx - 196608; int k = j >> 6, c = j & 63;
    Wp2t[(size_t)c*64 + k] = f2b(Wp2[j]);
  } else if (idx < 212992){             // W_fc rows 64..255 [192,64]
    int j = idx - 200704; int k = j >> 6, c = j & 63;
    Wfct[(size_t)c*192 + k] = f2b(Wfc[4096 + j]);
  }
}

// ==== fused layer 1, K-SPLIT + COALESCED OUTPUT ====
// Wave w: rows (w&1)*16..+15, K-half (w>>1). Output tile staged in LDS
// (aliases Pr+Hc after phase B) and stored as contiguous uint4.
__global__ __launch_bounds__(256) void k_l1(
    const float* __restrict__ x,        // [N,512] f32
    const ushort_t* __restrict__ Wp1t,  // [64,512] bf16
    const float* __restrict__ hc1,      // [128,64]
    const ushort_t* __restrict__ W1t,   // [256,128] bf16
    const float* __restrict__ att_s, const float* __restrict__ att_d,
    ushort_t* __restrict__ Hout,        // [N,256] bf16
    float* __restrict__ asrc, float* __restrict__ adst){
  __shared__ __align__(16) char Lbuf[16384];
  float* Pr = (float*)Lbuf;          // 8 KB partial acc [rowhalf][16][64]
  char*  Hc = Lbuf + 8192;           // 8 KB h1 tile (swizzled 256 B rows)
  char*  Ho = Lbuf;                  // 16 KB output tile (aliases Pr+Hc later)
  int tid = threadIdx.x;
  int w = tid >> 6, lane = tid & 63;
  int lr = lane & 15, lk = lane >> 4;
  int n0 = blockIdx.x * 32;
  int g = n0 >> 9;
  int sw = (lr & 7) << 4;
  int rowhalf = w & 1, khalf = w >> 1;
  // ---- phase A: 16 rows, K-half of 256, A register-loaded from global f32 ----
  f32x4 accA[4];
  #pragma unroll
  for (int ci = 0; ci < 4; ++ci) accA[ci] = (f32x4){0.f,0.f,0.f,0.f};
  const char* xrow = (const char*)x + (size_t)(n0 + rowhalf*16 + lr)*2048 + khalf*1024 + lk*32;
  const ushort_t* BbA = Wp1t + (size_t)lr*512 + khalf*256 + lk*8;
  #pragma unroll
  for (int j = 0; j < 8; ++j){
    float4 a0 = *(const float4*)(xrow + j*128);
    float4 a1 = *(const float4*)(xrow + j*128 + 16);
    bf16x8 af;
    af[0]=(short)f2b(a0.x); af[1]=(short)f2b(a0.y); af[2]=(short)f2b(a0.z); af[3]=(short)f2b(a0.w);
    af[4]=(short)f2b(a1.x); af[5]=(short)f2b(a1.y); af[6]=(short)f2b(a1.z); af[7]=(short)f2b(a1.w);
    #pragma unroll
    for (int ci = 0; ci < 4; ++ci){
      bf16x8 bfv = *(const bf16x8*)(BbA + (size_t)ci*16*512 + j*32);
      accA[ci] = __builtin_amdgcn_mfma_f32_16x16x32_bf16(af, bfv, accA[ci], 0, 0, 0);
    }
  }
  // K-half reduction: khalf==1 waves store, khalf==0 waves add
  if (khalf == 1){
    #pragma unroll
    for (int ci = 0; ci < 4; ++ci)
      #pragma unroll
      for (int q = 0; q < 4; ++q)
        Pr[(rowhalf*16 + ci*4 + q)*64 + lane] = accA[ci][q];
  }
  __syncthreads();
  if (khalf == 0){
    #pragma unroll
    for (int ci = 0; ci < 4; ++ci)
      #pragma unroll
      for (int q = 0; q < 4; ++q)
        accA[ci][q] += Pr[(rowhalf*16 + ci*4 + q)*64 + lane];
    // gate + write h1 tile rows rowhalf*16..+15 (swizzled 256 B rows)
    #pragma unroll
    for (int ci = 0; ci < 4; ++ci){
      int col = ci*16 + lr;
      float hc = hc1[g*64 + col];
      #pragma unroll
      for (int q = 0; q < 4; ++q){
        int row = rowhalf*16 + lk*4 + q;
        int swr = (row & 7) << 4;
        float hx = accA[ci][q];
        float gg = sigmoidf_(hx + hc);
        float fo = gg*hx + (1.f-gg)*hc;
        *(ushort_t*)(Hc + ((row*256 + col*2) ^ swr))        = f2b(fo);
        *(ushort_t*)(Hc + ((row*256 + (64 + col)*2) ^ swr)) = f2b(hx);
      }
    }
  }
  __syncthreads();
  // ---- phase B: H = h1 @ W1 (K=128); wave w = head w, 32 rows (2 row-tiles) ----
  int c0 = w * 64;
  f32x4 acc[2][4];
  #pragma unroll
  for (int ri = 0; ri < 2; ++ri)
    #pragma unroll
    for (int ci = 0; ci < 4; ++ci) acc[ri][ci] = (f32x4){0.f,0.f,0.f,0.f};
  #pragma unroll
  for (int k0 = 0; k0 < 128; k0 += 32){
    bf16x8 af[2], bfv[4];
    #pragma unroll
    for (int ri = 0; ri < 2; ++ri){
      int lg = (ri*16 + lr)*256 + (k0 + lk*8)*2;
      af[ri] = *(const bf16x8*)(Hc + (lg ^ sw));
    }
    #pragma unroll
    for (int ci = 0; ci < 4; ++ci)
      bfv[ci] = *(const bf16x8*)(W1t + (size_t)(c0 + ci*16 + lr)*128 + k0 + lk*8);
    #pragma unroll
    for (int ri = 0; ri < 2; ++ri)
      #pragma unroll
      for (int ci = 0; ci < 4; ++ci)
        acc[ri][ci] = __builtin_amdgcn_mfma_f32_16x16x32_bf16(af[ri], bfv[ci], acc[ri][ci], 0, 0, 0);
  }
  // att logits (register-only, before overwriting LDS)
  float as_[4], ad_[4];
  #pragma unroll
  for (int ci = 0; ci < 4; ++ci){
    as_[ci] = att_s[c0 + ci*16 + lr];
    ad_[ci] = att_d[c0 + ci*16 + lr];
  }
  #pragma unroll
  for (int ri = 0; ri < 2; ++ri){
    #pragma unroll
    for (int q = 0; q < 4; ++q){
      int row = n0 + ri*16 + lk*4 + q;
      float ps = 0.f, pd = 0.f;
      #pragma unroll
      for (int ci = 0; ci < 4; ++ci){
        float v = acc[ri][ci][q];
        ps = fmaf(v, as_[ci], ps);
        pd = fmaf(v, ad_[ci], pd);
      }
      #pragma unroll
      for (int m = 1; m < 16; m <<= 1){
        ps += __shfl_xor(ps, m);
        pd += __shfl_xor(pd, m);
      }
      if (lr == 0){
        asrc[(size_t)row*4 + w] = ps;
        adst[(size_t)row*4 + w] = pd;
      }
    }
  }
  __syncthreads();                     // all waves done reading Hc
  // stage output tile (32 rows x 512 B, swizzled) in Ho
  #pragma unroll
  for (int ri = 0; ri < 2; ++ri){
    #pragma unroll
    for (int q = 0; q < 4; ++q){
      int row = ri*16 + lk*4 + q;
      int swr = (row & 7) << 4;
      #pragma unroll
      for (int ci = 0; ci < 4; ++ci)
        *(ushort_t*)(Ho + ((row*512 + (c0 + ci*16 + lr)*2) ^ swr)) = f2b(acc[ri][ci][q]);
    }
  }
  __syncthreads();
  // coalesced store: 16 KB contiguous
  #pragma unroll
  for (int i = 0; i < 4; ++i){
    int p = i*4096 + tid*16;
    int row = p >> 9;
    uint4 v = *(const uint4*)(Ho + (p ^ ((row & 7) << 4)));
    *(uint4*)((char*)Hout + (size_t)n0*512 + p) = v;
  }
}

// ==== fused layer 2 + COALESCED OUTPUT (two 32-row passes through Sc) ====
__global__ __launch_bounds__(256) void k_l2(
    const ushort_t* __restrict__ xrb,   // [N,256] bf16
    const ushort_t* __restrict__ Wp2t,  // [64,64] bf16
    const float* __restrict__ hc2,      // [128,64]
    const ushort_t* __restrict__ W2t,   // [256,512] bf16
    const float* __restrict__ att_s, const float* __restrict__ att_d,
    ushort_t* __restrict__ Hout,        // [N,256] bf16
    float* __restrict__ asrc, float* __restrict__ adst){
  __shared__ __align__(16) ushort_t x3s[64*128];  // 16 KB x3 slab (swizzled)
  int tid = threadIdx.x;
  int w = tid >> 6, lane = tid & 63;
  int lr = lane & 15, lk = lane >> 4;
  int n0 = blockIdx.x * 64;
  int g = n0 >> 9;
  int sw = (lr & 7) << 4;
  char* Sc = (char*)x3s;
  const ushort_t* Ab = xrb + (size_t)(n0 + w*16 + lr)*256 + lk*8;
  int c0 = w * 64;
  f32x4 acc[4][4];
  #pragma unroll
  for (int ri = 0; ri < 4; ++ri)
    #pragma unroll
    for (int ci = 0; ci < 4; ++ci) acc[ri][ci] = (f32x4){0.f,0.f,0.f,0.f};
  for (int hd = 0; hd < 4; ++hd){
    // ---- phase A: hs rows w*16..+15 for head hd (K=64), A direct from global bf16 ----
    f32x4 acc2[4];
    #pragma unroll
    for (int ci = 0; ci < 4; ++ci) acc2[ci] = (f32x4){0.f,0.f,0.f,0.f};
    #pragma unroll
    for (int k0 = 0; k0 < 64; k0 += 32){
      bf16x8 af = *(const bf16x8*)(Ab + hd*64 + k0);
      #pragma unroll
      for (int ci = 0; ci < 4; ++ci){
        bf16x8 bfv = *(const bf16x8*)(Wp2t + (size_t)(ci*16 + lr)*64 + k0 + lk*8);
        acc2[ci] = __builtin_amdgcn_mfma_f32_16x16x32_bf16(af, bfv, acc2[ci], 0, 0, 0);
      }
    }
    #pragma unroll
    for (int ci = 0; ci < 4; ++ci){
      int col = ci*16 + lr;
      float hc = hc2[g*64 + col];
      #pragma unroll
      for (int q = 0; q < 4; ++q){
        int row = w*16 + lk*4 + q;
        int swr = (row & 7) << 4;
        float a = acc2[ci][q];
        float gg = sigmoidf_(a + hc);
        *(ushort_t*)(Sc + ((row*256 + col*2) ^ swr))        = f2b(gg*a + (1.f-gg)*hc);
        *(ushort_t*)(Sc + ((row*256 + (64 + col)*2) ^ swr)) = f2b(a);
      }
    }
    __syncthreads();
    // ---- phase B: K-slab 128 of the GAT GEMM, wave = output head ----
    #pragma unroll
    for (int k0 = 0; k0 < 128; k0 += 32){
      bf16x8 af[4], bfv[4];
      #pragma unroll
      for (int ri = 0; ri < 4; ++ri){
        int lg = (ri*16 + lr)*256 + (k0 + lk*8)*2;
        af[ri] = *(const bf16x8*)(Sc + (lg ^ sw));
      }
      #pragma unroll
      for (int ci = 0; ci < 4; ++ci)
        bfv[ci] = *(const bf16x8*)(W2t + (size_t)(c0 + ci*16 + lr)*512 + hd*128 + k0 + lk*8);
      #pragma unroll
      for (int ri = 0; ri < 4; ++ri)
        #pragma unroll
        for (int ci = 0; ci < 4; ++ci)
          acc[ri][ci] = __builtin_amdgcn_mfma_f32_16x16x32_bf16(af[ri], bfv[ci], acc[ri][ci], 0, 0, 0);
    }
    __syncthreads();
  }
  // att logits (register-only)
  float as_[4], ad_[4];
  #pragma unroll
  for (int ci = 0; ci < 4; ++ci){
    as_[ci] = att_s[c0 + ci*16 + lr];
    ad_[ci] = att_d[c0 + ci*16 + lr];
  }
  #pragma unroll
  for (int ri = 0; ri < 4; ++ri){
    #pragma unroll
    for (int q = 0; q < 4; ++q){
      int row = n0 + ri*16 + lk*4 + q;
      float ps = 0.f, pd = 0.f;
      #pragma unroll
      for (int ci = 0; ci < 4; ++ci){
        float v = acc[ri][ci][q];
        ps = fmaf(v, as_[ci], ps);
        pd = fmaf(v, ad_[ci], pd);
      }
      #pragma unroll
      for (int m = 1; m < 16; m <<= 1){
        ps += __shfl_xor(ps, m);
        pd += __shfl_xor(pd, m);
      }
      if (lr == 0){
        asrc[(size_t)row*4 + w] = ps;
        adst[(size_t)row*4 + w] = pd;
      }
    }
  }
  // coalesced output in two 32-row passes through Sc (dead after hd loop)
  #pragma unroll
  for (int half = 0; half < 2; ++half){
    #pragma unroll
    for (int rr = 0; rr < 2; ++rr){
      int ri = half*2 + rr;
      #pragma unroll
      for (int q = 0; q < 4; ++q){
        int row32 = rr*16 + lk*4 + q;
        int swr = (row32 & 7) << 4;
        #pragma unroll
        for (int ci = 0; ci < 4; ++ci)
          *(ushort_t*)(Sc + ((row32*512 + (c0 + ci*16 + lr)*2) ^ swr)) = f2b(acc[ri][ci][q]);
      }
    }
    __syncthreads();
    #pragma unroll
    for (int i = 0; i < 4; ++i){
      int p = i*4096 + tid*16;
      int row = p >> 9;
      uint4 v = *(const uint4*)(Sc + (p ^ ((row & 7) << 4)));
      *(uint4*)((char*)Hout + (size_t)(n0 + half*32)*512 + p) = v;
    }
    if (half == 0) __syncthreads();
  }
}

// ---------------- CSR build ----------------
__global__ void k_count(const int* __restrict__ ei, int* __restrict__ deg){
  int t = blockIdx.x*256 + threadIdx.x;
  int s = ei[t], d = ei[EE + t];
  atomicAdd(&deg[d], 1);
  atomicAdd(&deg[s], 1);
}

__global__ void k_scan1(const int* __restrict__ deg, int* __restrict__ offa,
                        int* __restrict__ bsum){
  __shared__ int sm[256];
  int tid = threadIdx.x, idx = blockIdx.x*256 + tid;
  int v = deg[idx] + 1;                 // +1 self-loop
  sm[tid] = v; __syncthreads();
  for (int o = 1; o < 256; o <<= 1){
    int t = (tid >= o) ? sm[tid-o] : 0;
    __syncthreads();
    sm[tid] += t;
    __syncthreads();
  }
  offa[idx] = sm[tid] - v;
  if (tid == 255) bsum[blockIdx.x] = sm[255];
}

__global__ void k_scan2(int* __restrict__ bsum){
  __shared__ int sm[256];
  int tid = threadIdx.x;
  int v = bsum[tid];
  sm[tid] = v; __syncthreads();
  for (int o = 1; o < 256; o <<= 1){
    int t = (tid >= o) ? sm[tid-o] : 0;
    __syncthreads();
    sm[tid] += t;
    __syncthreads();
  }
  bsum[tid] = sm[tid] - v;
}

__global__ void k_scan3(int* __restrict__ offa, const int* __restrict__ bsum){
  int idx = blockIdx.x*256 + threadIdx.x;
  offa[idx] += bsum[idx >> 8];
}

__global__ void k_fill(const int* __restrict__ ei, const int* __restrict__ offa,
                       int* __restrict__ cur, int* __restrict__ elist){
  int t = blockIdx.x*256 + threadIdx.x;
  int s = ei[t], d = ei[EE + t];
  int p = atomicAdd(&cur[d], 1); elist[offa[d] + p] = s;   // TD edge
  p = atomicAdd(&cur[s], 1);     elist[offa[s] + p] = d;   // BU (flipped) edge
  p = atomicAdd(&cur[t], 1);     elist[offa[t] + p] = t;   // self-loop (E==N)
}

// ------ GAT softmax-aggregate (h bf16); XCD-swizzled; e-values cached in LDS ------
template<int LAYER>
__global__ __launch_bounds__(256) void k_agg(const int* __restrict__ offa,
                                             const int* __restrict__ deg,
                                             const int* __restrict__ elist,
                                             const ushort_t* __restrict__ h,  // [N,256] bf16
                                             const float* __restrict__ asrc,
                                             const float* __restrict__ adst,
                                             const float* __restrict__ bias,
                                             ushort_t* __restrict__ outb,
                                             float* __restrict__ outf){
  __shared__ float eS[4][4][17][4];     // [wave][grp][edge(pad17)][head]
  __shared__ int   sS[4][4][17];
  int bid = blockIdx.x;
  int swz = (bid & 7) * (4096/8) + (bid >> 3);   // XCD-contiguous graphs
  int tid = threadIdx.x;
  int wave = tid >> 6, lane = tid & 63;
  int grp = lane >> 4, l = lane & 15;
  int n = swz*16 + wave*4 + grp;
  int o0 = offa[n], cnt = deg[n] + 1;
  float4 adv = *(const float4*)&adst[(size_t)n*4];
  float ad[4] = {adv.x, adv.y, adv.z, adv.w};
  int lim = (cnt < 16) ? cnt : 16;
  int s_l = elist[o0 + ((l < cnt) ? l : 0)];
  float4 asv = *(const float4*)&asrc[(size_t)s_l*4];
  float e_l[4];
  e_l[0] = lrelu_(asv.x + ad[0]); e_l[1] = lrelu_(asv.y + ad[1]);
  e_l[2] = lrelu_(asv.z + ad[2]); e_l[3] = lrelu_(asv.w + ad[3]);
  if (l < lim){
    sS[wave][grp][l] = s_l;
    *(float4*)&eS[wave][grp][l][0] = make_float4(e_l[0], e_l[1], e_l[2], e_l[3]);
  }
  float m[4];
  #pragma unroll
  for (int hh = 0; hh < 4; ++hh) m[hh] = (l < cnt) ? e_l[hh] : -1e30f;
  for (int i = 16 + l; i < cnt; i += 16){
    int s = elist[o0 + i];
    float4 a2 = *(const float4*)&asrc[(size_t)s*4];
    m[0] = fmaxf(m[0], lrelu_(a2.x + ad[0]));
    m[1] = fmaxf(m[1], lrelu_(a2.y + ad[1]));
    m[2] = fmaxf(m[2], lrelu_(a2.z + ad[2]));
    m[3] = fmaxf(m[3], lrelu_(a2.w + ad[3]));
  }
  #pragma unroll
  for (int mask = 1; mask < 16; mask <<= 1)
    #pragma unroll
    for (int hh = 0; hh < 4; ++hh) m[hh] = fmaxf(m[hh], __shfl_xor(m[hh], mask));
  int myh = l >> 2;
  float mm = m[myh];
  float den = 0.f;
  float accv[16] = {};
  for (int i = 0; i < lim; ++i){
    int s = sS[wave][grp][i];
    float e = eS[wave][grp][i][myh];
    float ex = __expf(e - mm);
    den += ex;
    const uint4* hp = (const uint4*)(h + (size_t)s*256 + l*16);
    uint4 h0 = hp[0], h1v = hp[1];
    uint_t uu[8] = {h0.x, h0.y, h0.z, h0.w, h1v.x, h1v.y, h1v.z, h1v.w};
    #pragma unroll
    for (int r = 0; r < 8; ++r){
      accv[2*r+0] = fmaf(ex, b2f(uu[r] & 0xffffu), accv[2*r+0]);
      accv[2*r+1] = fmaf(ex, b2f(uu[r] >> 16),     accv[2*r+1]);
    }
  }
  for (int i = 16; i < cnt; ++i){
    int s = elist[o0 + i];
    float4 a2 = *(const float4*)&asrc[(size_t)s*4];
    float e = lrelu_(((const float*)&a2)[myh] + ad[myh]);
    float ex = __expf(e - mm);
    den += ex;
    const uint4* hp = (const uint4*)(h + (size_t)s*256 + l*16);
    uint4 h0 = hp[0], h1v = hp[1];
    uint_t uu[8] = {h0.x, h0.y, h0.z, h0.w, h1v.x, h1v.y, h1v.z, h1v.w};
    #pragma unroll
    for (int r = 0; r < 8; ++r){
      accv[2*r+0] = fmaf(ex, b2f(uu[r] & 0xffffu), accv[2*r+0]);
      accv[2*r+1] = fmaf(ex, b2f(uu[r] >> 16),     accv[2*r+1]);
    }
  }
  float inv = 1.0f / den;
  if (LAYER == 1){
    #pragma unroll
    for (int r = 0; r < 4; ++r){
      int c = l*16 + r*4;
      float4 bv = *(const float4*)&bias[c];
      float o0v = fmaxf(accv[r*4+0]*inv + bv.x, 0.f);
      float o1v = fmaxf(accv[r*4+1]*inv + bv.y, 0.f);
      float o2v = fmaxf(accv[r*4+2]*inv + bv.z, 0.f);
      float o3v = fmaxf(accv[r*4+3]*inv + bv.w, 0.f);
      uint2 pk;
      pk.x = (uint_t)f2b(o0v) | ((uint_t)f2b(o1v) << 16);
      pk.y = (uint_t)f2b(o2v) | ((uint_t)f2b(o3v) << 16);
      *(uint2*)&outb[(size_t)n*256 + c] = pk;
    }
  } else {
    #pragma unroll
    for (int r = 0; r < 16; ++r) accv[r] *= inv;
    #pragma unroll
    for (int r = 0; r < 16; ++r){
      accv[r] += __shfl_xor(accv[r], 4);
      accv[r] += __shfl_xor(accv[r], 8);
    }
    if (l < 4){
      #pragma unroll
      for (int r = 0; r < 4; ++r){
        int c = l*16 + r*4;
        float4 bv = *(const float4*)&bias[c];
        float4 o;
        o.x = fmaxf(accv[r*4+0]*0.25f + bv.x, 0.f);
        o.y = fmaxf(accv[r*4+1]*0.25f + bv.y, 0.f);
        o.z = fmaxf(accv[r*4+2]*0.25f + bv.z, 0.f);
        o.w = fmaxf(accv[r*4+3]*0.25f + bv.w, 0.f);
        *(float4*)&outf[(size_t)n*64 + c] = o;
      }
    }
  }
}

// ---- pool via MFMA (k_base fused): block = 64 nodes x 64 outputs, K=192 ----
__global__ __launch_bounds__(256) void k_pool_mfma(
    const float* __restrict__ xr2,      // [N,64] f32
    const ushort_t* __restrict__ Wfct,  // [64,192] bf16 (W_fc[64:256]^T)
    const float* __restrict__ Wfc,      // [256,64] f32 (rows 0..63 used)
    const float* __restrict__ bfc,
    float* __restrict__ shat,
    float* __restrict__ ssum){
  __shared__ __align__(16) float xs[64][68];
  __shared__ float rls[64];
  __shared__ float bs[64];
  __shared__ float ls_sh[64];
  __shared__ float ls_s[64];
  int tid = threadIdx.x;
  int n0 = blockIdx.x * 64;
  int g = n0 >> 9;
  {
    int row = tid >> 4, col4 = (tid & 15) * 4;
    #pragma unroll
    for (int i = 0; i < 4; ++i){
      float4 v = *(const float4*)&xr2[(size_t)(n0 + row + i*16)*64 + col4];
      *(float4*)&xs[row + i*16][col4] = v;
    }
    if (tid < 16){
      float4 v = *(const float4*)&xr2[(size_t)((size_t)g*GGR)*64 + tid*4];
      *(float4*)&rls[tid*4] = v;
    }
    if (tid >= 128 && tid < 192){ ls_sh[tid-128] = 0.f; ls_s[tid-128] = 0.f; }
  }
  __syncthreads();
  if (tid < 64){
    float b = bfc[tid];
    for (int j = 0; j < 64; ++j) b = fmaf(rls[j], Wfc[j*64 + tid], b);
    bs[tid] = b;
  }
  __syncthreads();
  int w = tid >> 6, lane = tid & 63;
  int lr = lane & 15, lk = lane >> 4;
  f32x4 acc[4];
  #pragma unroll
  for (int ci = 0; ci < 4; ++ci) acc[ci] = (f32x4){0.f,0.f,0.f,0.f};
  int arow = w*16 + lr;
  #pragma unroll
  for (int k0 = 0; k0 < 192; k0 += 32){
    int seg = k0 >> 6;
    int cb = (k0 & 63) + lk*8;
    bf16x8 af;
    #pragma unroll
    for (int j = 0; j < 8; ++j){
      float xv = xs[arow][cb + j];
      float rv = rls[cb + j];
      float v = (seg == 0) ? xv : (seg == 1 ? xv*rv : fabsf(rv - xv));
      af[j] = (short)f2b(v);
    }
    #pragma unroll
    for (int ci = 0; ci < 4; ++ci){
      bf16x8 bfv = *(const bf16x8*)(Wfct + (size_t)(ci*16+lr)*192 + k0 + lk*8);
      acc[ci] = __builtin_amdgcn_mfma_f32_16x16x32_bf16(af, bfv, acc[ci], 0, 0, 0);
    }
  }
  float bsv[4];
  #pragma unroll
  for (int ci = 0; ci < 4; ++ci) bsv[ci] = bs[ci*16 + lr];
  float c_sh[4] = {0.f,0.f,0.f,0.f}, c_s[4] = {0.f,0.f,0.f,0.f};
  #pragma unroll
  for (int q = 0; q < 4; ++q){
    int rrow = w*16 + lk*4 + q;
    float t[4];
    float mx = -1e30f;
    #pragma unroll
    for (int ci = 0; ci < 4; ++ci){
      t[ci] = tanhf_(acc[ci][q] + bsv[ci]);
      mx = fmaxf(mx, t[ci]);
    }
    #pragma unroll
    for (int mask = 1; mask < 16; mask <<= 1) mx = fmaxf(mx, __shfl_xor(mx, mask));
    float e[4], s = 0.f;
    #pragma unroll
    for (int ci = 0; ci < 4; ++ci){ e[ci] = __expf(t[ci] - mx); s += e[ci]; }
    #pragma unroll
    for (int mask = 1; mask < 16; mask <<= 1) s += __shfl_xor(s, mask);
    float invs = 1.0f / s;
    #pragma unroll
    for (int ci = 0; ci < 4; ++ci){
      float xv = xs[rrow][ci*16 + lr];
      c_sh[ci] = fmaf(e[ci]*invs, xv, c_sh[ci]);
      c_s[ci] += xv;
    }
  }
  #pragma unroll
  for (int ci = 0; ci < 4; ++ci){
    c_sh[ci] += __shfl_xor(c_sh[ci], 16); c_sh[ci] += __shfl_xor(c_sh[ci], 32);
    c_s[ci]  += __shfl_xor(c_s[ci], 16);  c_s[ci]  += __shfl_xor(c_s[ci], 32);
  }
  if (lk == 0){
    #pragma unroll
    for (int ci = 0; ci < 4; ++ci){
      atomicAdd(&ls_sh[ci*16 + lr], c_sh[ci]);
      atomicAdd(&ls_s[ci*16 + lr], c_s[ci]);
    }
  }
  __syncthreads();
  if (tid < 64){
    atomicAdd(&shat[g*64 + tid], ls_sh[tid]);
    atomicAdd(&ssum[g*64 + tid], ls_s[tid]);
  }
}

// ------------- final logits + log_softmax -------------
__global__ void k_final(const float* __restrict__ shat, const float* __restrict__ ssum,
                        const float* __restrict__ Wc, const float* __restrict__ bc,
                        float* __restrict__ outp){
  int g = threadIdx.x;   // 128 graphs
  float l0 = bc[0], l1 = bc[1], l2 = bc[2], l3 = bc[3];
  const float s512 = 1.0f/512.0f;
  for (int j = 0; j < 64; ++j){
    float sh = shat[g*64 + j]*s512;
    float ss = ssum[g*64 + j]*s512;
    float4 w1 = *(const float4*)&Wc[j*4];
    float4 w2 = *(const float4*)&Wc[(64+j)*4];
    l0 = fmaf(sh, w1.x, fmaf(ss, w2.x, l0));
    l1 = fmaf(sh, w1.y, fmaf(ss, w2.y, l1));
    l2 = fmaf(sh, w1.z, fmaf(ss, w2.z, l2));
    l3 = fmaf(sh, w1.w, fmaf(ss, w2.w, l3));
  }
  float mx = fmaxf(fmaxf(l0,l1), fmaxf(l2,l3));
  float s = __expf(l0-mx)+__expf(l1-mx)+__expf(l2-mx)+__expf(l3-mx);
  float lse = mx + logf(s);
  outp[g*4+0] = l0 - lse;
  outp[g*4+1] = l1 - lse;
  outp[g*4+2] = l2 - lse;
  outp[g*4+3] = l3 - lse;
}

extern "C" void kernel_launch(void* const* d_in, const int* in_sizes, int n_in,
                              void* d_out, int out_size, void* d_ws, size_t ws_size,
                              hipStream_t stream){
  const float* x        = (const float*)d_in[0];
  const float* root     = (const float*)d_in[1];
  const int*   ei       = (const int*)d_in[2];
  const float* W_post1  = (const float*)d_in[5];
  const float* W_claim1 = (const float*)d_in[6];
  const float* W1       = (const float*)d_in[7];
  const float* att_src1 = (const float*)d_in[8];
  const float* att_dst1 = (const float*)d_in[9];
  const float* b1       = (const float*)d_in[10];
  const float* W_post2  = (const float*)d_in[11];
  const float* W_claim2 = (const float*)d_in[12];
  const float* W2       = (const float*)d_in[13];
  const float* att_src2 = (const float*)d_in[14];
  const float* att_dst2 = (const float*)d_in[15];
  const float* b2       = (const float*)d_in[16];
  const float* W_fc     = (const float*)d_in[17];
  const float* b_fc     = (const float*)d_in[18];
  const float* W_clf    = (const float*)d_in[19];
  const float* b_clf    = (const float*)d_in[20];
  float* out = (float*)d_out;

  char* w = (char*)d_ws;
  size_t o = 0;
  auto alloc = [&](size_t bytes)->char*{ char* p = w + o; o += (bytes + 255) & ~(size_t)255; return p; };
  ushort_t* RB   = (ushort_t*)alloc((size_t)NN*256*2);   // h2b then h3b
  ushort_t* xrb  = (ushort_t*)alloc((size_t)NN*256*2);
  float* xr2  = (float*)alloc((size_t)NN*64*4);
  float* asrc = (float*)alloc((size_t)NN*4*4);
  float* adst = (float*)alloc((size_t)NN*4*4);
  float* hc1  = (float*)alloc(128*64*4);
  float* hc2  = (float*)alloc(128*64*4);
  ushort_t* W1t  = (ushort_t*)alloc((size_t)256*128*2);
  ushort_t* W2t  = (ushort_t*)alloc((size_t)256*512*2);
  ushort_t* Wp1t = (ushort_t*)alloc((size_t)64*512*2);
  ushort_t* Wp2t = (ushort_t*)alloc((size_t)64*64*2);
  ushort_t* Wfct = (ushort_t*)alloc((size_t)64*192*2);
  int*   deg  = (int*)alloc((size_t)NN*4);
  int*   cur  = (int*)alloc((size_t)NN*4);      // adjacent to deg: one memset
  int*   offa = (int*)alloc((size_t)NN*4);
  int*   bsum = (int*)alloc(256*4);
  int*   elist= (int*)alloc((size_t)(2*EE+NN)*4);
  float* shat = (float*)alloc(128*64*4);
  float* ssumv= (float*)alloc(128*64*4);        // adjacent to shat: one memset

  ushort_t* h2b = RB;    // [N,256] bf16
  ushort_t* h3b = RB;    // [N,256] bf16 (h2b dead by then)

  hipMemsetAsync(deg,  0, (size_t)NN*8, stream);     // deg + cur
  hipMemsetAsync(shat, 0, 2*128*64*4, stream);       // shat + ssumv

  k_prep<<<960, 256, 0, stream>>>(W1, W2, W_post1, W_post2, W_fc,
                                  W1t, W2t, Wp1t, Wp2t, Wfct,
                                  root, W_claim1, W_claim2, hc1, hc2);
  k_count<<<256, 256, 0, stream>>>(ei, deg);
  k_scan1<<<256, 256, 0, stream>>>(deg, offa, bsum);
  k_scan2<<<1, 256, 0, stream>>>(bsum);
  k_scan3<<<256, 256, 0, stream>>>(offa, bsum);
  k_fill<<<256, 256, 0, stream>>>(ei, offa, cur, elist);
  k_l1<<<2048, 256, 0, stream>>>(x, Wp1t, hc1, W1t, att_src1, att_dst1, h2b, asrc, adst);
  k_agg<1><<<4096, 256, 0, stream>>>(offa, deg, elist, h2b, asrc, adst, b1, xrb, nullptr);
  k_l2<<<1024, 256, 0, stream>>>(xrb, Wp2t, hc2, W2t, att_src2, att_dst2, h3b, asrc, adst);
  k_agg<2><<<4096, 256, 0, stream>>>(offa, deg, elist, h3b, asrc, adst, b2, nullptr, xr2);
  k_pool_mfma<<<1024, 256, 0, stream>>>(xr2, Wfct, W_fc, b_fc, shat, ssumv);
  k_final<<<1, 128, 0, stream>>>(shat, ssumv, W_clf, b_clf, out);
  (void)in_sizes; (void)n_in; (void)out_size; (void)ws_size;
}

// Round 16
// 237.257 us; speedup vs baseline: 1.1095x; 1.1095x over previous
//
#include <hip/hip_runtime.h>
#include <math.h>

#define NN   65536
#define BB   128
#define GGR  512
#define EE   65536
#define INF_ 512
#define HIDD 64

typedef __attribute__((ext_vector_type(8))) short bf16x8;
typedef __attribute__((ext_vector_type(4))) float f32x4;
typedef unsigned short ushort_t;
typedef unsigned int uint_t;

static __device__ __forceinline__ float sigmoidf_(float x){ return 1.0f/(1.0f+__expf(-x)); }
static __device__ __forceinline__ float lrelu_(float x){ return x>=0.0f ? x : 0.2f*x; }
static __device__ __forceinline__ float tanhf_(float x){
  float e = __expf(2.f*x);
  return 1.f - 2.f/(e + 1.f);
}

// f32 -> bf16 bits, round-to-nearest-even
static __device__ __forceinline__ ushort_t f2b(float f){
  union { float f; uint_t u; } v; v.f = f;
  uint_t u = v.u;
  uint_t r = (u + 0x7fffu + ((u >> 16) & 1u)) >> 16;
  return (ushort_t)r;
}
// bf16 bits -> f32 (exact)
static __device__ __forceinline__ float b2f(uint_t u16){
  union { uint_t u; float f; } v; v.u = u16 << 16; return v.f;
}

// ---- fused prep: weight transpose+casts, plus hc1/hc2 (blocks >= 832) ----
__global__ void k_prep(const float* __restrict__ W1, const float* __restrict__ W2,
                       const float* __restrict__ Wp1, const float* __restrict__ Wp2,
                       const float* __restrict__ Wfc,
                       ushort_t* __restrict__ W1t, ushort_t* __restrict__ W2t,
                       ushort_t* __restrict__ Wp1t, ushort_t* __restrict__ Wp2t,
                       ushort_t* __restrict__ Wfct,
                       const float* __restrict__ root, const float* __restrict__ Wc1,
                       const float* __restrict__ Wc2, float* __restrict__ hc1,
                       float* __restrict__ hc2){
  if (blockIdx.x >= 832){
    int b = blockIdx.x - 832;
    int f = threadIdx.x;
    if (f < 64){
      const float* r = root + (size_t)b*INF_;
      float a1 = 0.f, a2 = 0.f;
      for (int k = 0; k < INF_; ++k){
        float rv = r[k];
        a1 = fmaf(rv, Wc1[k*HIDD+f], a1);
        a2 = fmaf(rv, Wc2[k*HIDD+f], a2);
      }
      hc1[b*HIDD+f] = a1; hc2[b*HIDD+f] = a2;
    }
    return;
  }
  int idx = blockIdx.x*256 + threadIdx.x;
  if (idx < 32768){                     // W1 [128,256]
    int k = idx >> 8, c = idx & 255;
    W1t[(size_t)c*128 + k] = f2b(W1[idx]);
  } else if (idx < 163840){             // W2 [512,256]
    int j = idx - 32768; int k = j >> 8, c = j & 255;
    W2t[(size_t)c*512 + k] = f2b(W2[j]);
  } else if (idx < 196608){             // W_post1 [512,64]
    int j = idx - 163840; int k = j >> 6, c = j & 63;
    Wp1t[(size_t)c*512 + k] = f2b(Wp1[j]);
  } else if (idx < 200704){             // W_post2 [64,64]
    int j = idx - 196608; int k = j >> 6, c = j & 63;
    Wp2t[(size_t)c*64 + k] = f2b(Wp2[j]);
  } else if (idx < 212992){             // W_fc rows 64..255 [192,64]
    int j = idx - 200704; int k = j >> 6, c = j & 63;
    Wfct[(size_t)c*192 + k] = f2b(Wfc[4096 + j]);
  }
}

// ==== fused layer 1, K-SPLIT + COALESCED OUTPUT (R15 form, proven 90 µs) ====
__global__ __launch_bounds__(256) void k_l1(
    const float* __restrict__ x,        // [N,512] f32
    const ushort_t* __restrict__ Wp1t,  // [64,512] bf16
    const float* __restrict__ hc1,      // [128,64]
    const ushort_t* __restrict__ W1t,   // [256,128] bf16
    const float* __restrict__ att_s, const float* __restrict__ att_d,
    ushort_t* __restrict__ Hout,        // [N,256] bf16
    float* __restrict__ asrc, float* __restrict__ adst){
  __shared__ __align__(16) char Lbuf[16384];
  float* Pr = (float*)Lbuf;          // 8 KB partial acc [rowhalf][16][64]
  char*  Hc = Lbuf + 8192;           // 8 KB h1 tile (swizzled 256 B rows)
  char*  Ho = Lbuf;                  // 16 KB output tile (aliases Pr+Hc later)
  int tid = threadIdx.x;
  int w = tid >> 6, lane = tid & 63;
  int lr = lane & 15, lk = lane >> 4;
  int n0 = blockIdx.x * 32;
  int g = n0 >> 9;
  int sw = (lr & 7) << 4;
  int rowhalf = w & 1, khalf = w >> 1;
  // ---- phase A: 16 rows, K-half of 256, A register-loaded from global f32 ----
  f32x4 accA[4];
  #pragma unroll
  for (int ci = 0; ci < 4; ++ci) accA[ci] = (f32x4){0.f,0.f,0.f,0.f};
  const char* xrow = (const char*)x + (size_t)(n0 + rowhalf*16 + lr)*2048 + khalf*1024 + lk*32;
  const ushort_t* BbA = Wp1t + (size_t)lr*512 + khalf*256 + lk*8;
  #pragma unroll
  for (int j = 0; j < 8; ++j){
    float4 a0 = *(const float4*)(xrow + j*128);
    float4 a1 = *(const float4*)(xrow + j*128 + 16);
    bf16x8 af;
    af[0]=(short)f2b(a0.x); af[1]=(short)f2b(a0.y); af[2]=(short)f2b(a0.z); af[3]=(short)f2b(a0.w);
    af[4]=(short)f2b(a1.x); af[5]=(short)f2b(a1.y); af[6]=(short)f2b(a1.z); af[7]=(short)f2b(a1.w);
    #pragma unroll
    for (int ci = 0; ci < 4; ++ci){
      bf16x8 bfv = *(const bf16x8*)(BbA + (size_t)ci*16*512 + j*32);
      accA[ci] = __builtin_amdgcn_mfma_f32_16x16x32_bf16(af, bfv, accA[ci], 0, 0, 0);
    }
  }
  // K-half reduction: khalf==1 waves store, khalf==0 waves add
  if (khalf == 1){
    #pragma unroll
    for (int ci = 0; ci < 4; ++ci)
      #pragma unroll
      for (int q = 0; q < 4; ++q)
        Pr[(rowhalf*16 + ci*4 + q)*64 + lane] = accA[ci][q];
  }
  __syncthreads();
  if (khalf == 0){
    #pragma unroll
    for (int ci = 0; ci < 4; ++ci)
      #pragma unroll
      for (int q = 0; q < 4; ++q)
        accA[ci][q] += Pr[(rowhalf*16 + ci*4 + q)*64 + lane];
    // gate + write h1 tile rows rowhalf*16..+15 (swizzled 256 B rows)
    #pragma unroll
    for (int ci = 0; ci < 4; ++ci){
      int col = ci*16 + lr;
      float hc = hc1[g*64 + col];
      #pragma unroll
      for (int q = 0; q < 4; ++q){
        int row = rowhalf*16 + lk*4 + q;
        int swr = (row & 7) << 4;
        float hx = accA[ci][q];
        float gg = sigmoidf_(hx + hc);
        float fo = gg*hx + (1.f-gg)*hc;
        *(ushort_t*)(Hc + ((row*256 + col*2) ^ swr))        = f2b(fo);
        *(ushort_t*)(Hc + ((row*256 + (64 + col)*2) ^ swr)) = f2b(hx);
      }
    }
  }
  __syncthreads();
  // ---- phase B: H = h1 @ W1 (K=128); wave w = head w, 32 rows (2 row-tiles) ----
  int c0 = w * 64;
  f32x4 acc[2][4];
  #pragma unroll
  for (int ri = 0; ri < 2; ++ri)
    #pragma unroll
    for (int ci = 0; ci < 4; ++ci) acc[ri][ci] = (f32x4){0.f,0.f,0.f,0.f};
  #pragma unroll
  for (int k0 = 0; k0 < 128; k0 += 32){
    bf16x8 af[2], bfv[4];
    #pragma unroll
    for (int ri = 0; ri < 2; ++ri){
      int lg = (ri*16 + lr)*256 + (k0 + lk*8)*2;
      af[ri] = *(const bf16x8*)(Hc + (lg ^ sw));
    }
    #pragma unroll
    for (int ci = 0; ci < 4; ++ci)
      bfv[ci] = *(const bf16x8*)(W1t + (size_t)(c0 + ci*16 + lr)*128 + k0 + lk*8);
    #pragma unroll
    for (int ri = 0; ri < 2; ++ri)
      #pragma unroll
      for (int ci = 0; ci < 4; ++ci)
        acc[ri][ci] = __builtin_amdgcn_mfma_f32_16x16x32_bf16(af[ri], bfv[ci], acc[ri][ci], 0, 0, 0);
  }
  // att logits (register-only, before overwriting LDS)
  float as_[4], ad_[4];
  #pragma unroll
  for (int ci = 0; ci < 4; ++ci){
    as_[ci] = att_s[c0 + ci*16 + lr];
    ad_[ci] = att_d[c0 + ci*16 + lr];
  }
  #pragma unroll
  for (int ri = 0; ri < 2; ++ri){
    #pragma unroll
    for (int q = 0; q < 4; ++q){
      int row = n0 + ri*16 + lk*4 + q;
      float ps = 0.f, pd = 0.f;
      #pragma unroll
      for (int ci = 0; ci < 4; ++ci){
        float v = acc[ri][ci][q];
        ps = fmaf(v, as_[ci], ps);
        pd = fmaf(v, ad_[ci], pd);
      }
      #pragma unroll
      for (int m = 1; m < 16; m <<= 1){
        ps += __shfl_xor(ps, m);
        pd += __shfl_xor(pd, m);
      }
      if (lr == 0){
        asrc[(size_t)row*4 + w] = ps;
        adst[(size_t)row*4 + w] = pd;
      }
    }
  }
  __syncthreads();                     // all waves done reading Hc
  // stage output tile (32 rows x 512 B, swizzled) in Ho
  #pragma unroll
  for (int ri = 0; ri < 2; ++ri){
    #pragma unroll
    for (int q = 0; q < 4; ++q){
      int row = ri*16 + lk*4 + q;
      int swr = (row & 7) << 4;
      #pragma unroll
      for (int ci = 0; ci < 4; ++ci)
        *(ushort_t*)(Ho + ((row*512 + (c0 + ci*16 + lr)*2) ^ swr)) = f2b(acc[ri][ci][q]);
    }
  }
  __syncthreads();
  // coalesced store: 16 KB contiguous
  #pragma unroll
  for (int i = 0; i < 4; ++i){
    int p = i*4096 + tid*16;
    int row = p >> 9;
    uint4 v = *(const uint4*)(Ho + (p ^ ((row & 7) << 4)));
    *(uint4*)((char*)Hout + (size_t)n0*512 + p) = v;
  }
}

// ==== fused layer 2 (R13/R9 form): x3 slab (per head) in LDS -> H = x3@W2 + att logits ====
__global__ __launch_bounds__(256) void k_l2(
    const ushort_t* __restrict__ xrb,   // [N,256] bf16
    const ushort_t* __restrict__ Wp2t,  // [64,64] bf16
    const float* __restrict__ hc2,      // [128,64]
    const ushort_t* __restrict__ W2t,   // [256,512] bf16
    const float* __restrict__ att_s, const float* __restrict__ att_d,
    ushort_t* __restrict__ Hout,        // [N,256] bf16
    float* __restrict__ asrc, float* __restrict__ adst){
  __shared__ __align__(16) ushort_t x3s[64*128];  // 16 KB x3 slab (swizzled)
  int tid = threadIdx.x;
  int w = tid >> 6, lane = tid & 63;
  int lr = lane & 15, lk = lane >> 4;
  int n0 = blockIdx.x * 64;
  int g = n0 >> 9;
  int sw = (lr & 7) << 4;
  char* Sc = (char*)x3s;
  const ushort_t* Ab = xrb + (size_t)(n0 + w*16 + lr)*256 + lk*8;
  int c0 = w * 64;
  f32x4 acc[4][4];
  #pragma unroll
  for (int ri = 0; ri < 4; ++ri)
    #pragma unroll
    for (int ci = 0; ci < 4; ++ci) acc[ri][ci] = (f32x4){0.f,0.f,0.f,0.f};
  for (int hd = 0; hd < 4; ++hd){
    // ---- phase A: hs rows w*16..+15 for head hd (K=64), A direct from global bf16 ----
    f32x4 acc2[4];
    #pragma unroll
    for (int ci = 0; ci < 4; ++ci) acc2[ci] = (f32x4){0.f,0.f,0.f,0.f};
    #pragma unroll
    for (int k0 = 0; k0 < 64; k0 += 32){
      bf16x8 af = *(const bf16x8*)(Ab + hd*64 + k0);
      #pragma unroll
      for (int ci = 0; ci < 4; ++ci){
        bf16x8 bfv = *(const bf16x8*)(Wp2t + (size_t)(ci*16 + lr)*64 + k0 + lk*8);
        acc2[ci] = __builtin_amdgcn_mfma_f32_16x16x32_bf16(af, bfv, acc2[ci], 0, 0, 0);
      }
    }
    #pragma unroll
    for (int ci = 0; ci < 4; ++ci){
      int col = ci*16 + lr;
      float hc = hc2[g*64 + col];
      #pragma unroll
      for (int q = 0; q < 4; ++q){
        int row = w*16 + lk*4 + q;
        int swr = (row & 7) << 4;
        float a = acc2[ci][q];
        float gg = sigmoidf_(a + hc);
        *(ushort_t*)(Sc + ((row*256 + col*2) ^ swr))        = f2b(gg*a + (1.f-gg)*hc);
        *(ushort_t*)(Sc + ((row*256 + (64 + col)*2) ^ swr)) = f2b(a);
      }
    }
    __syncthreads();
    // ---- phase B: K-slab 128 of the GAT GEMM, wave = output head ----
    #pragma unroll
    for (int k0 = 0; k0 < 128; k0 += 32){
      bf16x8 af[4], bfv[4];
      #pragma unroll
      for (int ri = 0; ri < 4; ++ri){
        int lg = (ri*16 + lr)*256 + (k0 + lk*8)*2;
        af[ri] = *(const bf16x8*)(Sc + (lg ^ sw));
      }
      #pragma unroll
      for (int ci = 0; ci < 4; ++ci)
        bfv[ci] = *(const bf16x8*)(W2t + (size_t)(c0 + ci*16 + lr)*512 + hd*128 + k0 + lk*8);
      #pragma unroll
      for (int ri = 0; ri < 4; ++ri)
        #pragma unroll
        for (int ci = 0; ci < 4; ++ci)
          acc[ri][ci] = __builtin_amdgcn_mfma_f32_16x16x32_bf16(af[ri], bfv[ci], acc[ri][ci], 0, 0, 0);
    }
    if (hd < 3) __syncthreads();
  }
  float as_[4], ad_[4];
  #pragma unroll
  for (int ci = 0; ci < 4; ++ci){
    as_[ci] = att_s[c0 + ci*16 + lr];
    ad_[ci] = att_d[c0 + ci*16 + lr];
  }
  #pragma unroll
  for (int ri = 0; ri < 4; ++ri){
    #pragma unroll
    for (int q = 0; q < 4; ++q){
      int row = n0 + ri*16 + lk*4 + q;
      float ps = 0.f, pd = 0.f;
      #pragma unroll
      for (int ci = 0; ci < 4; ++ci){
        float v = acc[ri][ci][q];
        Hout[(size_t)row*256 + c0 + ci*16 + lr] = f2b(v);
        ps = fmaf(v, as_[ci], ps);
        pd = fmaf(v, ad_[ci], pd);
      }
      #pragma unroll
      for (int m = 1; m < 16; m <<= 1){
        ps += __shfl_xor(ps, m);
        pd += __shfl_xor(pd, m);
      }
      if (lr == 0){
        asrc[(size_t)row*4 + w] = ps;
        adst[(size_t)row*4 + w] = pd;
      }
    }
  }
}

// ---------------- CSR build ----------------
__global__ void k_count(const int* __restrict__ ei, int* __restrict__ deg){
  int t = blockIdx.x*256 + threadIdx.x;
  int s = ei[t], d = ei[EE + t];
  atomicAdd(&deg[d], 1);
  atomicAdd(&deg[s], 1);
}

__global__ void k_scan1(const int* __restrict__ deg, int* __restrict__ offa,
                        int* __restrict__ bsum){
  __shared__ int sm[256];
  int tid = threadIdx.x, idx = blockIdx.x*256 + tid;
  int v = deg[idx] + 1;                 // +1 self-loop
  sm[tid] = v; __syncthreads();
  for (int o = 1; o < 256; o <<= 1){
    int t = (tid >= o) ? sm[tid-o] : 0;
    __syncthreads();
    sm[tid] += t;
    __syncthreads();
  }
  offa[idx] = sm[tid] - v;
  if (tid == 255) bsum[blockIdx.x] = sm[255];
}

__global__ void k_scan2(int* __restrict__ bsum){
  __shared__ int sm[256];
  int tid = threadIdx.x;
  int v = bsum[tid];
  sm[tid] = v; __syncthreads();
  for (int o = 1; o < 256; o <<= 1){
    int t = (tid >= o) ? sm[tid-o] : 0;
    __syncthreads();
    sm[tid] += t;
    __syncthreads();
  }
  bsum[tid] = sm[tid] - v;
}

__global__ void k_scan3(int* __restrict__ offa, const int* __restrict__ bsum){
  int idx = blockIdx.x*256 + threadIdx.x;
  offa[idx] += bsum[idx >> 8];
}

__global__ void k_fill(const int* __restrict__ ei, const int* __restrict__ offa,
                       int* __restrict__ cur, int* __restrict__ elist){
  int t = blockIdx.x*256 + threadIdx.x;
  int s = ei[t], d = ei[EE + t];
  int p = atomicAdd(&cur[d], 1); elist[offa[d] + p] = s;   // TD edge
  p = atomicAdd(&cur[s], 1);     elist[offa[s] + p] = d;   // BU (flipped) edge
  p = atomicAdd(&cur[t], 1);     elist[offa[t] + p] = t;   // self-loop (E==N)
}

// ------ GAT softmax-aggregate (h bf16); XCD-swizzled; e-values cached in LDS ------
template<int LAYER>
__global__ __launch_bounds__(256) void k_agg(const int* __restrict__ offa,
                                             const int* __restrict__ deg,
                                             const int* __restrict__ elist,
                                             const ushort_t* __restrict__ h,  // [N,256] bf16
                                             const float* __restrict__ asrc,
                                             const float* __restrict__ adst,
                                             const float* __restrict__ bias,
                                             ushort_t* __restrict__ outb,
                                             float* __restrict__ outf){
  __shared__ float eS[4][4][17][4];     // [wave][grp][edge(pad17)][head]
  __shared__ int   sS[4][4][17];
  int bid = blockIdx.x;
  int swz = (bid & 7) * (4096/8) + (bid >> 3);   // XCD-contiguous graphs
  int tid = threadIdx.x;
  int wave = tid >> 6, lane = tid & 63;
  int grp = lane >> 4, l = lane & 15;
  int n = swz*16 + wave*4 + grp;
  int o0 = offa[n], cnt = deg[n] + 1;
  float4 adv = *(const float4*)&adst[(size_t)n*4];
  float ad[4] = {adv.x, adv.y, adv.z, adv.w};
  int lim = (cnt < 16) ? cnt : 16;
  int s_l = elist[o0 + ((l < cnt) ? l : 0)];
  float4 asv = *(const float4*)&asrc[(size_t)s_l*4];
  float e_l[4];
  e_l[0] = lrelu_(asv.x + ad[0]); e_l[1] = lrelu_(asv.y + ad[1]);
  e_l[2] = lrelu_(asv.z + ad[2]); e_l[3] = lrelu_(asv.w + ad[3]);
  if (l < lim){
    sS[wave][grp][l] = s_l;
    *(float4*)&eS[wave][grp][l][0] = make_float4(e_l[0], e_l[1], e_l[2], e_l[3]);
  }
  float m[4];
  #pragma unroll
  for (int hh = 0; hh < 4; ++hh) m[hh] = (l < cnt) ? e_l[hh] : -1e30f;
  for (int i = 16 + l; i < cnt; i += 16){
    int s = elist[o0 + i];
    float4 a2 = *(const float4*)&asrc[(size_t)s*4];
    m[0] = fmaxf(m[0], lrelu_(a2.x + ad[0]));
    m[1] = fmaxf(m[1], lrelu_(a2.y + ad[1]));
    m[2] = fmaxf(m[2], lrelu_(a2.z + ad[2]));
    m[3] = fmaxf(m[3], lrelu_(a2.w + ad[3]));
  }
  #pragma unroll
  for (int mask = 1; mask < 16; mask <<= 1)
    #pragma unroll
    for (int hh = 0; hh < 4; ++hh) m[hh] = fmaxf(m[hh], __shfl_xor(m[hh], mask));
  int myh = l >> 2;
  float mm = m[myh];
  float den = 0.f;
  float accv[16] = {};
  for (int i = 0; i < lim; ++i){
    int s = sS[wave][grp][i];
    float e = eS[wave][grp][i][myh];
    float ex = __expf(e - mm);
    den += ex;
    const uint4* hp = (const uint4*)(h + (size_t)s*256 + l*16);
    uint4 h0 = hp[0], h1v = hp[1];
    uint_t uu[8] = {h0.x, h0.y, h0.z, h0.w, h1v.x, h1v.y, h1v.z, h1v.w};
    #pragma unroll
    for (int r = 0; r < 8; ++r){
      accv[2*r+0] = fmaf(ex, b2f(uu[r] & 0xffffu), accv[2*r+0]);
      accv[2*r+1] = fmaf(ex, b2f(uu[r] >> 16),     accv[2*r+1]);
    }
  }
  for (int i = 16; i < cnt; ++i){
    int s = elist[o0 + i];
    float4 a2 = *(const float4*)&asrc[(size_t)s*4];
    float e = lrelu_(((const float*)&a2)[myh] + ad[myh]);
    float ex = __expf(e - mm);
    den += ex;
    const uint4* hp = (const uint4*)(h + (size_t)s*256 + l*16);
    uint4 h0 = hp[0], h1v = hp[1];
    uint_t uu[8] = {h0.x, h0.y, h0.z, h0.w, h1v.x, h1v.y, h1v.z, h1v.w};
    #pragma unroll
    for (int r = 0; r < 8; ++r){
      accv[2*r+0] = fmaf(ex, b2f(uu[r] & 0xffffu), accv[2*r+0]);
      accv[2*r+1] = fmaf(ex, b2f(uu[r] >> 16),     accv[2*r+1]);
    }
  }
  float inv = 1.0f / den;
  if (LAYER == 1){
    #pragma unroll
    for (int r = 0; r < 4; ++r){
      int c = l*16 + r*4;
      float4 bv = *(const float4*)&bias[c];
      float o0v = fmaxf(accv[r*4+0]*inv + bv.x, 0.f);
      float o1v = fmaxf(accv[r*4+1]*inv + bv.y, 0.f);
      float o2v = fmaxf(accv[r*4+2]*inv + bv.z, 0.f);
      float o3v = fmaxf(accv[r*4+3]*inv + bv.w, 0.f);
      uint2 pk;
      pk.x = (uint_t)f2b(o0v) | ((uint_t)f2b(o1v) << 16);
      pk.y = (uint_t)f2b(o2v) | ((uint_t)f2b(o3v) << 16);
      *(uint2*)&outb[(size_t)n*256 + c] = pk;
    }
  } else {
    #pragma unroll
    for (int r = 0; r < 16; ++r) accv[r] *= inv;
    #pragma unroll
    for (int r = 0; r < 16; ++r){
      accv[r] += __shfl_xor(accv[r], 4);
      accv[r] += __shfl_xor(accv[r], 8);
    }
    if (l < 4){
      #pragma unroll
      for (int r = 0; r < 4; ++r){
        int c = l*16 + r*4;
        float4 bv = *(const float4*)&bias[c];
        float4 o;
        o.x = fmaxf(accv[r*4+0]*0.25f + bv.x, 0.f);
        o.y = fmaxf(accv[r*4+1]*0.25f + bv.y, 0.f);
        o.z = fmaxf(accv[r*4+2]*0.25f + bv.z, 0.f);
        o.w = fmaxf(accv[r*4+3]*0.25f + bv.w, 0.f);
        *(float4*)&outf[(size_t)n*64 + c] = o;
      }
    }
  }
}

// ---- pool via MFMA (k_base fused): block = 64 nodes x 64 outputs, K=192 ----
__global__ __launch_bounds__(256) void k_pool_mfma(
    const float* __restrict__ xr2,      // [N,64] f32
    const ushort_t* __restrict__ Wfct,  // [64,192] bf16 (W_fc[64:256]^T)
    const float* __restrict__ Wfc,      // [256,64] f32 (rows 0..63 used)
    const float* __restrict__ bfc,
    float* __restrict__ shat,
    float* __restrict__ ssum){
  __shared__ __align__(16) float xs[64][68];
  __shared__ float rls[64];
  __shared__ float bs[64];
  __shared__ float ls_sh[64];
  __shared__ float ls_s[64];
  int tid = threadIdx.x;
  int n0 = blockIdx.x * 64;
  int g = n0 >> 9;
  {
    int row = tid >> 4, col4 = (tid & 15) * 4;
    #pragma unroll
    for (int i = 0; i < 4; ++i){
      float4 v = *(const float4*)&xr2[(size_t)(n0 + row + i*16)*64 + col4];
      *(float4*)&xs[row + i*16][col4] = v;
    }
    if (tid < 16){
      float4 v = *(const float4*)&xr2[(size_t)((size_t)g*GGR)*64 + tid*4];
      *(float4*)&rls[tid*4] = v;
    }
    if (tid >= 128 && tid < 192){ ls_sh[tid-128] = 0.f; ls_s[tid-128] = 0.f; }
  }
  __syncthreads();
  if (tid < 64){
    float b = bfc[tid];
    for (int j = 0; j < 64; ++j) b = fmaf(rls[j], Wfc[j*64 + tid], b);
    bs[tid] = b;
  }
  __syncthreads();
  int w = tid >> 6, lane = tid & 63;
  int lr = lane & 15, lk = lane >> 4;
  f32x4 acc[4];
  #pragma unroll
  for (int ci = 0; ci < 4; ++ci) acc[ci] = (f32x4){0.f,0.f,0.f,0.f};
  int arow = w*16 + lr;
  #pragma unroll
  for (int k0 = 0; k0 < 192; k0 += 32){
    int seg = k0 >> 6;
    int cb = (k0 & 63) + lk*8;
    bf16x8 af;
    #pragma unroll
    for (int j = 0; j < 8; ++j){
      float xv = xs[arow][cb + j];
      float rv = rls[cb + j];
      float v = (seg == 0) ? xv : (seg == 1 ? xv*rv : fabsf(rv - xv));
      af[j] = (short)f2b(v);
    }
    #pragma unroll
    for (int ci = 0; ci < 4; ++ci){
      bf16x8 bfv = *(const bf16x8*)(Wfct + (size_t)(ci*16+lr)*192 + k0 + lk*8);
      acc[ci] = __builtin_amdgcn_mfma_f32_16x16x32_bf16(af, bfv, acc[ci], 0, 0, 0);
    }
  }
  float bsv[4];
  #pragma unroll
  for (int ci = 0; ci < 4; ++ci) bsv[ci] = bs[ci*16 + lr];
  float c_sh[4] = {0.f,0.f,0.f,0.f}, c_s[4] = {0.f,0.f,0.f,0.f};
  #pragma unroll
  for (int q = 0; q < 4; ++q){
    int rrow = w*16 + lk*4 + q;
    float t[4];
    float mx = -1e30f;
    #pragma unroll
    for (int ci = 0; ci < 4; ++ci){
      t[ci] = tanhf_(acc[ci][q] + bsv[ci]);
      mx = fmaxf(mx, t[ci]);
    }
    #pragma unroll
    for (int mask = 1; mask < 16; mask <<= 1) mx = fmaxf(mx, __shfl_xor(mx, mask));
    float e[4], s = 0.f;
    #pragma unroll
    for (int ci = 0; ci < 4; ++ci){ e[ci] = __expf(t[ci] - mx); s += e[ci]; }
    #pragma unroll
    for (int mask = 1; mask < 16; mask <<= 1) s += __shfl_xor(s, mask);
    float invs = 1.0f / s;
    #pragma unroll
    for (int ci = 0; ci < 4; ++ci){
      float xv = xs[rrow][ci*16 + lr];
      c_sh[ci] = fmaf(e[ci]*invs, xv, c_sh[ci]);
      c_s[ci] += xv;
    }
  }
  #pragma unroll
  for (int ci = 0; ci < 4; ++ci){
    c_sh[ci] += __shfl_xor(c_sh[ci], 16); c_sh[ci] += __shfl_xor(c_sh[ci], 32);
    c_s[ci]  += __shfl_xor(c_s[ci], 16);  c_s[ci]  += __shfl_xor(c_s[ci], 32);
  }
  if (lk == 0){
    #pragma unroll
    for (int ci = 0; ci < 4; ++ci){
      atomicAdd(&ls_sh[ci*16 + lr], c_sh[ci]);
      atomicAdd(&ls_s[ci*16 + lr], c_s[ci]);
    }
  }
  __syncthreads();
  if (tid < 64){
    atomicAdd(&shat[g*64 + tid], ls_sh[tid]);
    atomicAdd(&ssum[g*64 + tid], ls_s[tid]);
  }
}

// ------------- final logits + log_softmax -------------
__global__ void k_final(const float* __restrict__ shat, const float* __restrict__ ssum,
                        const float* __restrict__ Wc, const float* __restrict__ bc,
                        float* __restrict__ outp){
  int g = threadIdx.x;   // 128 graphs
  float l0 = bc[0], l1 = bc[1], l2 = bc[2], l3 = bc[3];
  const float s512 = 1.0f/512.0f;
  for (int j = 0; j < 64; ++j){
    float sh = shat[g*64 + j]*s512;
    float ss = ssum[g*64 + j]*s512;
    float4 w1 = *(const float4*)&Wc[j*4];
    float4 w2 = *(const float4*)&Wc[(64+j)*4];
    l0 = fmaf(sh, w1.x, fmaf(ss, w2.x, l0));
    l1 = fmaf(sh, w1.y, fmaf(ss, w2.y, l1));
    l2 = fmaf(sh, w1.z, fmaf(ss, w2.z, l2));
    l3 = fmaf(sh, w1.w, fmaf(ss, w2.w, l3));
  }
  float mx = fmaxf(fmaxf(l0,l1), fmaxf(l2,l3));
  float s = __expf(l0-mx)+__expf(l1-mx)+__expf(l2-mx)+__expf(l3-mx);
  float lse = mx + logf(s);
  outp[g*4+0] = l0 - lse;
  outp[g*4+1] = l1 - lse;
  outp[g*4+2] = l2 - lse;
  outp[g*4+3] = l3 - lse;
}

extern "C" void kernel_launch(void* const* d_in, const int* in_sizes, int n_in,
                              void* d_out, int out_size, void* d_ws, size_t ws_size,
                              hipStream_t stream){
  const float* x        = (const float*)d_in[0];
  const float* root     = (const float*)d_in[1];
  const int*   ei       = (const int*)d_in[2];
  const float* W_post1  = (const float*)d_in[5];
  const float* W_claim1 = (const float*)d_in[6];
  const float* W1       = (const float*)d_in[7];
  const float* att_src1 = (const float*)d_in[8];
  const float* att_dst1 = (const float*)d_in[9];
  const float* b1       = (const float*)d_in[10];
  const float* W_post2  = (const float*)d_in[11];
  const float* W_claim2 = (const float*)d_in[12];
  const float* W2       = (const float*)d_in[13];
  const float* att_src2 = (const float*)d_in[14];
  const float* att_dst2 = (const float*)d_in[15];
  const float* b2       = (const float*)d_in[16];
  const float* W_fc     = (const float*)d_in[17];
  const float* b_fc     = (const float*)d_in[18];
  const float* W_clf    = (const float*)d_in[19];
  const float* b_clf    = (const float*)d_in[20];
  float* out = (float*)d_out;

  char* w = (char*)d_ws;
  size_t o = 0;
  auto alloc = [&](size_t bytes)->char*{ char* p = w + o; o += (bytes + 255) & ~(size_t)255; return p; };
  ushort_t* RB   = (ushort_t*)alloc((size_t)NN*256*2);   // h2b then h3b
  ushort_t* xrb  = (ushort_t*)alloc((size_t)NN*256*2);
  float* xr2  = (float*)alloc((size_t)NN*64*4);
  float* asrc = (float*)alloc((size_t)NN*4*4);
  float* adst = (float*)alloc((size_t)NN*4*4);
  float* hc1  = (float*)alloc(128*64*4);
  float* hc2  = (float*)alloc(128*64*4);
  ushort_t* W1t  = (ushort_t*)alloc((size_t)256*128*2);
  ushort_t* W2t  = (ushort_t*)alloc((size_t)256*512*2);
  ushort_t* Wp1t = (ushort_t*)alloc((size_t)64*512*2);
  ushort_t* Wp2t = (ushort_t*)alloc((size_t)64*64*2);
  ushort_t* Wfct = (ushort_t*)alloc((size_t)64*192*2);
  int*   deg  = (int*)alloc((size_t)NN*4);
  int*   cur  = (int*)alloc((size_t)NN*4);      // adjacent to deg: one memset
  int*   offa = (int*)alloc((size_t)NN*4);
  int*   bsum = (int*)alloc(256*4);
  int*   elist= (int*)alloc((size_t)(2*EE+NN)*4);
  float* shat = (float*)alloc(128*64*4);
  float* ssumv= (float*)alloc(128*64*4);        // adjacent to shat: one memset

  ushort_t* h2b = RB;    // [N,256] bf16
  ushort_t* h3b = RB;    // [N,256] bf16 (h2b dead by then)

  hipMemsetAsync(deg,  0, (size_t)NN*8, stream);     // deg + cur
  hipMemsetAsync(shat, 0, 2*128*64*4, stream);       // shat + ssumv

  k_prep<<<960, 256, 0, stream>>>(W1, W2, W_post1, W_post2, W_fc,
                                  W1t, W2t, Wp1t, Wp2t, Wfct,
                                  root, W_claim1, W_claim2, hc1, hc2);
  k_count<<<256, 256, 0, stream>>>(ei, deg);
  k_scan1<<<256, 256, 0, stream>>>(deg, offa, bsum);
  k_scan2<<<1, 256, 0, stream>>>(bsum);
  k_scan3<<<256, 256, 0, stream>>>(offa, bsum);
  k_fill<<<256, 256, 0, stream>>>(ei, offa, cur, elist);
  k_l1<<<2048, 256, 0, stream>>>(x, Wp1t, hc1, W1t, att_src1, att_dst1, h2b, asrc, adst);
  k_agg<1><<<4096, 256, 0, stream>>>(offa, deg, elist, h2b, asrc, adst, b1, xrb, nullptr);
  k_l2<<<1024, 256, 0, stream>>>(xrb, Wp2t, hc2, W2t, att_src2, att_dst2, h3b, asrc, adst);
  k_agg<2><<<4096, 256, 0, stream>>>(offa, deg, elist, h3b, asrc, adst, b2, nullptr, xr2);
  k_pool_mfma<<<1024, 256, 0, stream>>>(xr2, Wfct, W_fc, b_fc, shat, ssumv);
  k_final<<<1, 128, 0, stream>>>(shat, ssumv, W_clf, b_clf, out);
  (void)in_sizes; (void)n_in; (void)out_size; (void)ws_size;
}